// Round 4
// baseline (685.843 us; speedup 1.0000x reference)
//
#include <hip/hip_runtime.h>

#define NN 100000
#define NE 1600000
#define NBKT 391          // ceil(NN/256) buckets of 256 dst nodes
#define CAP 8192          // bucket capacity (mean 4092, ~64 sigma headroom)
#define NEG 0.2f

// ---------------- kU: precompute u_s[8][4], u_d[8][4] (W1 . att vectors) ----------------
__global__ void kU_prep(
    const float* __restrict__ W1, const float* __restrict__ atts,
    const float* __restrict__ attd, float* __restrict__ us, float* __restrict__ ud)
{
    int t = threadIdx.x;           // 64 threads
    if (t >= 64) return;
    int half = t >> 5;             // 0: us, 1: ud
    int i = t & 31;
    int h = i >> 2, k = i & 3;
    const float* att = half ? attd : atts;
    float acc = 0.f;
    #pragma unroll
    for (int j = 0; j < 8; j++)
        acc += W1[k * 64 + h * 8 + j] * att[h * 8 + j];
    (half ? ud : us)[h * 4 + k] = acc;
}

// ---------------- kP1: partition edges into dst-range buckets ----------------
__global__ __launch_bounds__(256) void kP1_bucket(
    const int* __restrict__ ei, int* __restrict__ bcnt, unsigned* __restrict__ bpack)
{
    int e = blockIdx.x * 256 + threadIdx.x;
    if (e >= NE) return;
    int s = ei[e], d = ei[NE + e];
    int b = d >> 8;
    int pos = atomicAdd(&bcnt[b], 1);
    if (pos < CAP)
        bpack[(size_t)b * CAP + pos] = ((unsigned)s << 8) | (unsigned)(d & 255);
}

// ---------------- kS: exclusive scan of bucket counts (single block) ----------------
__global__ __launch_bounds__(512) void kS_scan(
    const int* __restrict__ bcnt, int* __restrict__ bktoff, int* __restrict__ row)
{
    __shared__ int s[512];
    int t = threadIdx.x;
    int v = (t < NBKT) ? bcnt[t] : 0;
    s[t] = v;
    __syncthreads();
    #pragma unroll
    for (int o = 1; o < 512; o <<= 1) {
        int u = (t >= o) ? s[t - o] : 0;
        __syncthreads();
        s[t] += u;
        __syncthreads();
    }
    if (t < NBKT) bktoff[t] = s[t] - v;
    if (t == 0) row[NN] = NE;
}

// ---------------- kP2: per-bucket LDS counting sort -> row + esrc ----------------
__global__ __launch_bounds__(1024) void kP2_build(
    const int* __restrict__ bcnt, const int* __restrict__ bktoff,
    const unsigned* __restrict__ bpack, int* __restrict__ row, int* __restrict__ esrc)
{
    __shared__ int lh[256], lsc[256], lcur[256];
    __shared__ int sarr[CAP];
    int b = blockIdx.x;
    int t = threadIdx.x;
    int cnt = bcnt[b];
    if (cnt > CAP) cnt = CAP;
    const unsigned* bp = &bpack[(size_t)b * CAP];
    if (t < 256) lh[t] = 0;
    __syncthreads();
    for (int i = t; i < cnt; i += 1024)
        atomicAdd(&lh[bp[i] & 255u], 1);
    __syncthreads();
    if (t < 256) lsc[t] = lh[t];
    __syncthreads();
    #pragma unroll
    for (int o = 1; o < 256; o <<= 1) {
        int u = 0;
        if (t < 256 && t >= o) u = lsc[t - o];
        __syncthreads();
        if (t < 256) lsc[t] += u;
        __syncthreads();
    }
    int base = bktoff[b];
    if (t < 256) {
        int ex = lsc[t] - lh[t];
        lcur[t] = ex;
        int node = b * 256 + t;
        if (node < NN) row[node] = base + ex;
    }
    __syncthreads();
    for (int i = t; i < cnt; i += 1024) {
        unsigned u = bp[i];
        int pos = atomicAdd(&lcur[u & 255u], 1);
        sarr[pos] = (int)(u >> 8);
    }
    __syncthreads();
    for (int i = t; i < cnt; i += 1024)
        esrc[base + i] = sarr[i];
}

// ---------------- kE: layer-1 full (recompute-from-x) + ELU + W2 dot (wave/dst) ----------------
__global__ __launch_bounds__(256) void kE_l1agg(
    const int* __restrict__ row, const int* __restrict__ esrc,
    const float* __restrict__ x, const float* __restrict__ us,
    const float* __restrict__ ud, const float* __restrict__ W1,
    const float* __restrict__ b1, const float* __restrict__ W2,
    float* __restrict__ h2)
{
    int wave = blockIdx.x * 4 + (threadIdx.x >> 6);
    int lane = threadIdx.x & 63;
    if (wave >= NN) return;
    int dst = wave;
    int start = row[dst], end = row[dst + 1];
    int myh = lane >> 3;

    // per-lane constants: W1 column (4), u_s for my head (4)
    float w0 = W1[lane], w1 = W1[64 + lane], w2 = W1[128 + lane], w3 = W1[192 + lane];
    float4 u  = *reinterpret_cast<const float4*>(&us[myh * 4]);
    float4 vd = *reinterpret_cast<const float4*>(&ud[myh * 4]);
    float4 xd = *reinterpret_cast<const float4*>(&x[(size_t)dst * 4]);
    float adj = xd.x * vd.x + xd.y * vd.y + xd.z * vd.z + xd.w * vd.w;

    // self-loop term (src = dst), handled inline
    float acc, den;
    {
        float asv = xd.x * u.x + xd.y * u.y + xd.z * u.z + xd.w * u.w;
        float v = asv + adj;
        v = v > 0.f ? v : NEG * v;
        float p = __expf(v);
        den = p;
        acc = p * (xd.x * w0 + xd.y * w1 + xd.z * w2 + xd.w * w3);
    }
    #pragma unroll 4
    for (int i = start; i < end; ++i) {
        int s = esrc[i];
        float4 xs = *reinterpret_cast<const float4*>(&x[(size_t)s * 4]);
        float asv = xs.x * u.x + xs.y * u.y + xs.z * u.z + xs.w * u.w;
        float v = asv + adj;
        v = v > 0.f ? v : NEG * v;            // leaky_relu
        float p = __expf(v);                  // softmax shift-invariant; logits bounded
        den += p;
        float hc = xs.x * w0 + xs.y * w1 + xs.z * w2 + xs.w * w3;
        acc += p * hc;
    }

    // normalize + b1 + ELU + W2 dot, wave-reduce
    float v = acc / (den + 1e-16f) + b1[lane];
    v = v > 0.f ? v : (__expf(v) - 1.f);
    float w = v * W2[lane];
    #pragma unroll
    for (int o = 32; o; o >>= 1) w += __shfl_xor(w, o);
    if (lane == 0) h2[dst] = w;
}

// ---------------- kF: layer-2 aggregate + sigmoid (16 lanes per dst) ----------------
__global__ __launch_bounds__(256) void kF_l2agg(
    const int* __restrict__ row, const int* __restrict__ esrc,
    const float* __restrict__ h2, const float* __restrict__ as2,
    const float* __restrict__ ad2, const float* __restrict__ b2,
    float* __restrict__ out)
{
    int grp = threadIdx.x >> 4;
    int sub = threadIdx.x & 15;
    int dst = blockIdx.x * 16 + grp;
    if (dst >= NN) return;
    int start = row[dst], end = row[dst + 1];
    float a_s = as2[0], a_d = ad2[0];
    float hdv = h2[dst];
    float hd = hdv * a_d;

    float den = 0.f, num = 0.f;
    if (sub == 0) {                           // self-loop
        float v = hdv * a_s + hd;
        v = v > 0.f ? v : NEG * v;
        float p = __expf(v);
        den = p;
        num = p * hdv;
    }
    for (int i = start + sub; i < end; i += 16) {
        float hs = h2[esrc[i]];
        float v = hs * a_s + hd;
        v = v > 0.f ? v : NEG * v;
        float p = __expf(v);
        den += p;
        num += p * hs;
    }
    #pragma unroll
    for (int o = 8; o; o >>= 1) {
        den += __shfl_xor(den, o, 16);
        num += __shfl_xor(num, o, 16);
    }
    if (sub == 0) {
        float v = num / (den + 1e-16f) + b2[0];
        out[dst] = 1.f / (1.f + __expf(-v));
    }
}

extern "C" void kernel_launch(void* const* d_in, const int* in_sizes, int n_in,
                              void* d_out, int out_size, void* d_ws, size_t ws_size,
                              hipStream_t stream) {
    const float* x     = (const float*)d_in[0];
    const int*   ei    = (const int*)d_in[1];
    const float* W1    = (const float*)d_in[2];
    const float* atts1 = (const float*)d_in[3];
    const float* attd1 = (const float*)d_in[4];
    const float* b1    = (const float*)d_in[5];
    const float* W2    = (const float*)d_in[6];
    const float* atts2 = (const float*)d_in[7];
    const float* attd2 = (const float*)d_in[8];
    const float* b2    = (const float*)d_in[9];
    float* out = (float*)d_out;

    float* w = (float*)d_ws;
    float* us = w;                       // 32
    float* ud = w + 32;                  // 32
    float* h2 = w + 64;                  // N
    int* ibase  = (int*)(w + 64 + (size_t)NN);
    int* bcnt   = ibase;                           // NBKT (pad 512)
    int* bktoff = ibase + 512;                     // NBKT (pad 512)
    int* row    = ibase + 1024;                    // N+1 (pad N+64)
    int* esrc   = ibase + 1024 + NN + 64;          // NE
    unsigned* bpack = (unsigned*)(ibase + 1024 + NN + 64 + NE);  // NBKT*CAP

    dim3 blk(256);
    dim3 gE((NE + 255) / 256);        // 6250
    dim3 gW((NN + 3) / 4);            // 25000, wave per dst
    dim3 gF((NN + 15) / 16);          // 6250, 16 dst per block

    hipLaunchKernelGGL(kU_prep, dim3(1), dim3(64), 0, stream, W1, atts1, attd1, us, ud);
    hipMemsetAsync(bcnt, 0, NBKT * sizeof(int), stream);
    hipLaunchKernelGGL(kP1_bucket, gE, blk, 0, stream, ei, bcnt, bpack);
    hipLaunchKernelGGL(kS_scan, dim3(1), dim3(512), 0, stream, bcnt, bktoff, row);
    hipLaunchKernelGGL(kP2_build, dim3(NBKT), dim3(1024), 0, stream, bcnt, bktoff, bpack, row, esrc);
    hipLaunchKernelGGL(kE_l1agg, gW, blk, 0, stream, row, esrc, x, us, ud, W1, b1, W2, h2);
    hipLaunchKernelGGL(kF_l2agg, gF, blk, 0, stream, row, esrc, h2, atts2, attd2, b2, out);
}

// Round 5
// 142.783 us; speedup vs baseline: 4.8034x; 4.8034x over previous
//
#include <hip/hip_runtime.h>

#define NN 100000
#define NE 1600000
#define NBKT 391          // ceil(NN/256) buckets of 256 dst nodes
#define CAP 8192          // bucket capacity (mean 4096, sigma ~64)
#define TILE 16384        // edges per kP1 block
#define NTILE ((NE + TILE - 1) / TILE)   // 98
#define NEG 0.2f

// ---------------- kU: precompute u_s[8][4], u_d[8][4] (W1 . att vectors) ----------------
__global__ void kU_prep(
    const float* __restrict__ W1, const float* __restrict__ atts,
    const float* __restrict__ attd, float* __restrict__ us, float* __restrict__ ud)
{
    int t = threadIdx.x;           // 64 threads
    if (t >= 64) return;
    int half = t >> 5;             // 0: us, 1: ud
    int i = t & 31;
    int h = i >> 2, k = i & 3;
    const float* att = half ? attd : atts;
    float acc = 0.f;
    #pragma unroll
    for (int j = 0; j < 8; j++)
        acc += W1[k * 64 + h * 8 + j] * att[h * 8 + j];
    (half ? ud : us)[h * 4 + k] = acc;
}

// ---------------- kP1: tiled bucket partition (LDS hist + batch reserve + coalesced out) ----------------
__global__ __launch_bounds__(1024) void kP1_tile(
    const int* __restrict__ ei, int* __restrict__ bcnt, unsigned* __restrict__ bpack)
{
    __shared__ unsigned sarr[TILE];          // 64 KB
    __shared__ int lh[512], lsc[512], lgb[512];
    int t = threadIdx.x;
    int e0 = blockIdx.x * TILE;
    int n = NE - e0; if (n > TILE) n = TILE;

    if (t < 512) lh[t] = 0;
    __syncthreads();
    // pass A: LDS histogram of dst>>8
    for (int i = t; i < n; i += 1024) {
        int d = ei[NE + e0 + i];
        atomicAdd(&lh[d >> 8], 1);
    }
    __syncthreads();
    // inclusive scan of counts (512-entry Hillis-Steele)
    if (t < 512) lsc[t] = lh[t];
    __syncthreads();
    #pragma unroll
    for (int o = 1; o < 512; o <<= 1) {
        int u = 0;
        if (t < 512 && t >= o) u = lsc[t - o];
        __syncthreads();
        if (t < 512) lsc[t] += u;
        __syncthreads();
    }
    // batch-reserve global space: ONE atomic per (block,bucket)
    if (t < NBKT && lh[t] > 0) lgb[t] = atomicAdd(&bcnt[t], lh[t]);
    __syncthreads();
    // turn lh into LDS cursor at exclusive base
    if (t < 512) lh[t] = lsc[t] - lh[t];
    __syncthreads();
    // pass B: counting-sort tile into LDS
    for (int i = t; i < n; i += 1024) {
        int s = ei[e0 + i], d = ei[NE + e0 + i];
        int b = d >> 8;
        int pos = atomicAdd(&lh[b], 1);
        sarr[pos] = ((unsigned)s << 8) | (unsigned)(d & 255);
    }
    __syncthreads();
    // coalesced write-out: wave w handles buckets w, w+16, ...
    int wave = t >> 6, lane = t & 63;
    for (int b = wave; b < NBKT; b += 16) {
        int start = (b == 0) ? 0 : lsc[b - 1];
        int cntb = lsc[b] - start;
        if (cntb == 0) continue;
        int gb = lgb[b];
        unsigned* dstp = &bpack[(size_t)b * CAP];
        for (int j = lane; j < cntb; j += 64) {
            int gpos = gb + j;
            if (gpos < CAP) dstp[gpos] = sarr[start + j];
        }
    }
}

// ---------------- kS: exclusive scan of bucket counts (single block) ----------------
__global__ __launch_bounds__(512) void kS_scan(
    const int* __restrict__ bcnt, int* __restrict__ bktoff, int* __restrict__ row)
{
    __shared__ int s[512];
    int t = threadIdx.x;
    int v = (t < NBKT) ? bcnt[t] : 0;
    s[t] = v;
    __syncthreads();
    #pragma unroll
    for (int o = 1; o < 512; o <<= 1) {
        int u = (t >= o) ? s[t - o] : 0;
        __syncthreads();
        s[t] += u;
        __syncthreads();
    }
    if (t < NBKT) bktoff[t] = s[t] - v;
    if (t == 0) row[NN] = NE;
}

// ---------------- kP2: per-bucket LDS counting sort -> row + esrc ----------------
__global__ __launch_bounds__(1024) void kP2_build(
    const int* __restrict__ bcnt, const int* __restrict__ bktoff,
    const unsigned* __restrict__ bpack, int* __restrict__ row, int* __restrict__ esrc)
{
    __shared__ int lh[256], lsc[256], lcur[256];
    __shared__ int sarr[CAP];
    int b = blockIdx.x;
    int t = threadIdx.x;
    int cnt = bcnt[b];
    if (cnt > CAP) cnt = CAP;
    const unsigned* bp = &bpack[(size_t)b * CAP];
    if (t < 256) lh[t] = 0;
    __syncthreads();
    for (int i = t; i < cnt; i += 1024)
        atomicAdd(&lh[bp[i] & 255u], 1);
    __syncthreads();
    if (t < 256) lsc[t] = lh[t];
    __syncthreads();
    #pragma unroll
    for (int o = 1; o < 256; o <<= 1) {
        int u = 0;
        if (t < 256 && t >= o) u = lsc[t - o];
        __syncthreads();
        if (t < 256) lsc[t] += u;
        __syncthreads();
    }
    int base = bktoff[b];
    if (t < 256) {
        int ex = lsc[t] - lh[t];
        lcur[t] = ex;
        int node = b * 256 + t;
        if (node < NN) row[node] = base + ex;
    }
    __syncthreads();
    for (int i = t; i < cnt; i += 1024) {
        unsigned u = bp[i];
        int pos = atomicAdd(&lcur[u & 255u], 1);
        sarr[pos] = (int)(u >> 8);
    }
    __syncthreads();
    for (int i = t; i < cnt; i += 1024)
        esrc[base + i] = sarr[i];
}

// ---------------- kE: layer-1 full (recompute-from-x) + ELU + W2 dot (wave/dst) ----------------
__global__ __launch_bounds__(256) void kE_l1agg(
    const int* __restrict__ row, const int* __restrict__ esrc,
    const float* __restrict__ x, const float* __restrict__ us,
    const float* __restrict__ ud, const float* __restrict__ W1,
    const float* __restrict__ b1, const float* __restrict__ W2,
    float* __restrict__ h2)
{
    int wave = blockIdx.x * 4 + (threadIdx.x >> 6);
    int lane = threadIdx.x & 63;
    if (wave >= NN) return;
    int dst = wave;
    int start = row[dst], end = row[dst + 1];
    int myh = lane >> 3;

    // per-lane constants: W1 column (4), u_s for my head (4)
    float w0 = W1[lane], w1 = W1[64 + lane], w2 = W1[128 + lane], w3 = W1[192 + lane];
    float4 u  = *reinterpret_cast<const float4*>(&us[myh * 4]);
    float4 vd = *reinterpret_cast<const float4*>(&ud[myh * 4]);
    float4 xd = *reinterpret_cast<const float4*>(&x[(size_t)dst * 4]);
    float adj = xd.x * vd.x + xd.y * vd.y + xd.z * vd.z + xd.w * vd.w;

    // self-loop term (src = dst), handled inline
    float acc, den;
    {
        float asv = xd.x * u.x + xd.y * u.y + xd.z * u.z + xd.w * u.w;
        float v = asv + adj;
        v = v > 0.f ? v : NEG * v;
        float p = __expf(v);
        den = p;
        acc = p * (xd.x * w0 + xd.y * w1 + xd.z * w2 + xd.w * w3);
    }
    #pragma unroll 4
    for (int i = start; i < end; ++i) {
        int s = esrc[i];
        float4 xs = *reinterpret_cast<const float4*>(&x[(size_t)s * 4]);
        float asv = xs.x * u.x + xs.y * u.y + xs.z * u.z + xs.w * u.w;
        float v = asv + adj;
        v = v > 0.f ? v : NEG * v;            // leaky_relu
        float p = __expf(v);                  // softmax shift-invariant; logits bounded
        den += p;
        float hc = xs.x * w0 + xs.y * w1 + xs.z * w2 + xs.w * w3;
        acc += p * hc;
    }

    // normalize + b1 + ELU + W2 dot, wave-reduce
    float v = acc / (den + 1e-16f) + b1[lane];
    v = v > 0.f ? v : (__expf(v) - 1.f);
    float w = v * W2[lane];
    #pragma unroll
    for (int o = 32; o; o >>= 1) w += __shfl_xor(w, o);
    if (lane == 0) h2[dst] = w;
}

// ---------------- kF: layer-2 aggregate + sigmoid (16 lanes per dst) ----------------
__global__ __launch_bounds__(256) void kF_l2agg(
    const int* __restrict__ row, const int* __restrict__ esrc,
    const float* __restrict__ h2, const float* __restrict__ as2,
    const float* __restrict__ ad2, const float* __restrict__ b2,
    float* __restrict__ out)
{
    int grp = threadIdx.x >> 4;
    int sub = threadIdx.x & 15;
    int dst = blockIdx.x * 16 + grp;
    if (dst >= NN) return;
    int start = row[dst], end = row[dst + 1];
    float a_s = as2[0], a_d = ad2[0];
    float hdv = h2[dst];
    float hd = hdv * a_d;

    float den = 0.f, num = 0.f;
    if (sub == 0) {                           // self-loop
        float v = hdv * a_s + hd;
        v = v > 0.f ? v : NEG * v;
        float p = __expf(v);
        den = p;
        num = p * hdv;
    }
    for (int i = start + sub; i < end; i += 16) {
        float hs = h2[esrc[i]];
        float v = hs * a_s + hd;
        v = v > 0.f ? v : NEG * v;
        float p = __expf(v);
        den += p;
        num += p * hs;
    }
    #pragma unroll
    for (int o = 8; o; o >>= 1) {
        den += __shfl_xor(den, o, 16);
        num += __shfl_xor(num, o, 16);
    }
    if (sub == 0) {
        float v = num / (den + 1e-16f) + b2[0];
        out[dst] = 1.f / (1.f + __expf(-v));
    }
}

extern "C" void kernel_launch(void* const* d_in, const int* in_sizes, int n_in,
                              void* d_out, int out_size, void* d_ws, size_t ws_size,
                              hipStream_t stream) {
    const float* x     = (const float*)d_in[0];
    const int*   ei    = (const int*)d_in[1];
    const float* W1    = (const float*)d_in[2];
    const float* atts1 = (const float*)d_in[3];
    const float* attd1 = (const float*)d_in[4];
    const float* b1    = (const float*)d_in[5];
    const float* W2    = (const float*)d_in[6];
    const float* atts2 = (const float*)d_in[7];
    const float* attd2 = (const float*)d_in[8];
    const float* b2    = (const float*)d_in[9];
    float* out = (float*)d_out;

    float* w = (float*)d_ws;
    float* us = w;                       // 32
    float* ud = w + 32;                  // 32
    float* h2 = w + 64;                  // N
    int* ibase  = (int*)(w + 64 + (size_t)NN);
    int* bcnt   = ibase;                           // NBKT (pad 512)
    int* bktoff = ibase + 512;                     // NBKT (pad 512)
    int* row    = ibase + 1024;                    // N+1 (pad N+64)
    int* esrc   = ibase + 1024 + NN + 64;          // NE
    unsigned* bpack = (unsigned*)(ibase + 1024 + NN + 64 + NE);  // NBKT*CAP

    dim3 gW((NN + 3) / 4);            // 25000, wave per dst
    dim3 gF((NN + 15) / 16);          // 6250, 16 dst per block

    hipLaunchKernelGGL(kU_prep, dim3(1), dim3(64), 0, stream, W1, atts1, attd1, us, ud);
    hipMemsetAsync(bcnt, 0, NBKT * sizeof(int), stream);
    hipLaunchKernelGGL(kP1_tile, dim3(NTILE), dim3(1024), 0, stream, ei, bcnt, bpack);
    hipLaunchKernelGGL(kS_scan, dim3(1), dim3(512), 0, stream, bcnt, bktoff, row);
    hipLaunchKernelGGL(kP2_build, dim3(NBKT), dim3(1024), 0, stream, bcnt, bktoff, bpack, row, esrc);
    hipLaunchKernelGGL(kE_l1agg, gW, dim3(256), 0, stream, row, esrc, x, us, ud, W1, b1, W2, h2);
    hipLaunchKernelGGL(kF_l2agg, gF, dim3(256), 0, stream, row, esrc, h2, atts2, attd2, b2, out);
}

// Round 6
// 115.066 us; speedup vs baseline: 5.9604x; 1.2409x over previous
//
#include <hip/hip_runtime.h>

#define NN 100000
#define NE 1600000
#define NBKT 391          // ceil(NN/256) buckets of 256 dst nodes
#define CAP 8192          // bucket capacity (mean 4096, sigma ~64)
#define TILE 16384        // edges per kP1 block
#define NTILE ((NE + TILE - 1) / TILE)   // 98
#define NEG 0.2f

// ---------------- kU: precompute u_s[8][4], u_d[8][4] (W1 . att vectors) ----------------
__global__ void kU_prep(
    const float* __restrict__ W1, const float* __restrict__ atts,
    const float* __restrict__ attd, float* __restrict__ us, float* __restrict__ ud)
{
    int t = threadIdx.x;           // 64 threads
    if (t >= 64) return;
    int half = t >> 5;             // 0: us, 1: ud
    int i = t & 31;
    int h = i >> 2, k = i & 3;
    const float* att = half ? attd : atts;
    float acc = 0.f;
    #pragma unroll
    for (int j = 0; j < 8; j++)
        acc += W1[k * 64 + h * 8 + j] * att[h * 8 + j];
    (half ? ud : us)[h * 4 + k] = acc;
}

// ---------------- kP1: tiled bucket partition (LDS hist + batch reserve + coalesced out) ----------------
__global__ __launch_bounds__(1024) void kP1_tile(
    const int* __restrict__ ei, int* __restrict__ bcnt, unsigned* __restrict__ bpack)
{
    __shared__ unsigned sarr[TILE];          // 64 KB
    __shared__ int lh[512], lsc[512], lgb[512];
    int t = threadIdx.x;
    int e0 = blockIdx.x * TILE;
    int n = NE - e0; if (n > TILE) n = TILE;

    if (t < 512) lh[t] = 0;
    __syncthreads();
    // pass A: LDS histogram of dst>>8
    for (int i = t; i < n; i += 1024) {
        int d = ei[NE + e0 + i];
        atomicAdd(&lh[d >> 8], 1);
    }
    __syncthreads();
    // inclusive scan of counts (512-entry Hillis-Steele)
    if (t < 512) lsc[t] = lh[t];
    __syncthreads();
    #pragma unroll
    for (int o = 1; o < 512; o <<= 1) {
        int u = 0;
        if (t < 512 && t >= o) u = lsc[t - o];
        __syncthreads();
        if (t < 512) lsc[t] += u;
        __syncthreads();
    }
    // batch-reserve global space: ONE atomic per (block,bucket)
    if (t < NBKT && lh[t] > 0) lgb[t] = atomicAdd(&bcnt[t], lh[t]);
    __syncthreads();
    // turn lh into LDS cursor at exclusive base
    if (t < 512) lh[t] = lsc[t] - lh[t];
    __syncthreads();
    // pass B: counting-sort tile into LDS
    for (int i = t; i < n; i += 1024) {
        int s = ei[e0 + i], d = ei[NE + e0 + i];
        int b = d >> 8;
        int pos = atomicAdd(&lh[b], 1);
        sarr[pos] = ((unsigned)s << 8) | (unsigned)(d & 255);
    }
    __syncthreads();
    // coalesced write-out: wave w handles buckets w, w+16, ...
    int wave = t >> 6, lane = t & 63;
    for (int b = wave; b < NBKT; b += 16) {
        int start = (b == 0) ? 0 : lsc[b - 1];
        int cntb = lsc[b] - start;
        if (cntb == 0) continue;
        int gb = lgb[b];
        unsigned* dstp = &bpack[(size_t)b * CAP];
        for (int j = lane; j < cntb; j += 64) {
            int gpos = gb + j;
            if (gpos < CAP) dstp[gpos] = sarr[start + j];
        }
    }
}

// ---------------- kS: exclusive scan of bucket counts (single block) ----------------
__global__ __launch_bounds__(512) void kS_scan(
    const int* __restrict__ bcnt, int* __restrict__ bktoff, int* __restrict__ row)
{
    __shared__ int s[512];
    int t = threadIdx.x;
    int v = (t < NBKT) ? bcnt[t] : 0;
    s[t] = v;
    __syncthreads();
    #pragma unroll
    for (int o = 1; o < 512; o <<= 1) {
        int u = (t >= o) ? s[t - o] : 0;
        __syncthreads();
        s[t] += u;
        __syncthreads();
    }
    if (t < NBKT) bktoff[t] = s[t] - v;
    if (t == 0) row[NN] = NE;
}

// ---------------- kP2: per-bucket LDS counting sort -> row + esrc ----------------
__global__ __launch_bounds__(1024) void kP2_build(
    const int* __restrict__ bcnt, const int* __restrict__ bktoff,
    const unsigned* __restrict__ bpack, int* __restrict__ row, int* __restrict__ esrc)
{
    __shared__ int lh[256], lsc[256], lcur[256];
    __shared__ int sarr[CAP];
    int b = blockIdx.x;
    int t = threadIdx.x;
    int cnt = bcnt[b];
    if (cnt > CAP) cnt = CAP;
    const unsigned* bp = &bpack[(size_t)b * CAP];
    if (t < 256) lh[t] = 0;
    __syncthreads();
    for (int i = t; i < cnt; i += 1024)
        atomicAdd(&lh[bp[i] & 255u], 1);
    __syncthreads();
    if (t < 256) lsc[t] = lh[t];
    __syncthreads();
    #pragma unroll
    for (int o = 1; o < 256; o <<= 1) {
        int u = 0;
        if (t < 256 && t >= o) u = lsc[t - o];
        __syncthreads();
        if (t < 256) lsc[t] += u;
        __syncthreads();
    }
    int base = bktoff[b];
    if (t < 256) {
        int ex = lsc[t] - lh[t];
        lcur[t] = ex;
        int node = b * 256 + t;
        if (node < NN) row[node] = base + ex;
    }
    __syncthreads();
    for (int i = t; i < cnt; i += 1024) {
        unsigned u = bp[i];
        int pos = atomicAdd(&lcur[u & 255u], 1);
        sarr[pos] = (int)(u >> 8);
    }
    __syncthreads();
    for (int i = t; i < cnt; i += 1024)
        esrc[base + i] = sarr[i];
}

// ---------------- kE: layer-1: lane=(edge-slot,head); aggregate x, project once ----------------
__global__ __launch_bounds__(256) void kE_l1agg(
    const int* __restrict__ row, const int* __restrict__ esrc,
    const float* __restrict__ x, const float* __restrict__ us,
    const float* __restrict__ ud, const float* __restrict__ W1,
    const float* __restrict__ b1, const float* __restrict__ W2,
    float* __restrict__ h2)
{
    int wave = blockIdx.x * 4 + (threadIdx.x >> 6);
    int lane = threadIdx.x & 63;
    if (wave >= NN) return;
    int dst = wave;
    int start = row[dst], end = row[dst + 1];
    int m = end - start;            // real in-edges; slot j==m is the self-loop
    int h  = lane & 7;              // my head
    int e8 = lane >> 3;             // my edge slot
    int c  = h * 8 + e8;            // my output channel (unique per lane)

    float4 u  = *reinterpret_cast<const float4*>(&us[h * 4]);
    float4 vd = *reinterpret_cast<const float4*>(&ud[h * 4]);
    float4 xd = *reinterpret_cast<const float4*>(&x[(size_t)dst * 4]);
    float adj = xd.x * vd.x + xd.y * vd.y + xd.z * vd.z + xd.w * vd.w;

    // per-edge: p = exp(leaky(x[s].u_h + adj)); xagg += p*x[s]; den += p
    float xa0 = 0.f, xa1 = 0.f, xa2 = 0.f, xa3 = 0.f, den = 0.f;
    for (int j = e8; j <= m; j += 8) {
        int s = (j < m) ? esrc[start + j] : dst;
        float4 xs = *reinterpret_cast<const float4*>(&x[(size_t)s * 4]);
        float a = fmaf(xs.x, u.x, fmaf(xs.y, u.y, fmaf(xs.z, u.z, fmaf(xs.w, u.w, adj))));
        a = fmaxf(a, NEG * a);                // leaky_relu (valid both signs)
        float p = __expf(a);                  // softmax shift-invariant; logits bounded
        den += p;
        xa0 = fmaf(p, xs.x, xa0);
        xa1 = fmaf(p, xs.y, xa1);
        xa2 = fmaf(p, xs.z, xa2);
        xa3 = fmaf(p, xs.w, xa3);
    }
    // butterfly over edge slots (lane bits 3..5) -> all lanes of head h hold full sums
    #pragma unroll
    for (int o = 8; o < 64; o <<= 1) {
        xa0 += __shfl_xor(xa0, o);
        xa1 += __shfl_xor(xa1, o);
        xa2 += __shfl_xor(xa2, o);
        xa3 += __shfl_xor(xa3, o);
        den += __shfl_xor(den, o);
    }
    // project channel c: out1 = (xagg . W1[:,c]) / den + b1; ELU; dot W2
    float w0 = W1[c], w1 = W1[64 + c], w2 = W1[128 + c], w3 = W1[192 + c];
    float v = (xa0 * w0 + xa1 * w1 + xa2 * w2 + xa3 * w3) / (den + 1e-16f) + b1[c];
    v = v > 0.f ? v : (__expf(v) - 1.f);
    float wv = v * W2[c];
    #pragma unroll
    for (int o = 1; o < 64; o <<= 1) wv += __shfl_xor(wv, o);
    if (lane == 0) h2[dst] = wv;
}

// ---------------- kF: layer-2 aggregate + sigmoid (16 lanes per dst) ----------------
__global__ __launch_bounds__(256) void kF_l2agg(
    const int* __restrict__ row, const int* __restrict__ esrc,
    const float* __restrict__ h2, const float* __restrict__ as2,
    const float* __restrict__ ad2, const float* __restrict__ b2,
    float* __restrict__ out)
{
    int grp = threadIdx.x >> 4;
    int sub = threadIdx.x & 15;
    int dst = blockIdx.x * 16 + grp;
    if (dst >= NN) return;
    int start = row[dst], end = row[dst + 1];
    float a_s = as2[0], a_d = ad2[0];
    float hdv = h2[dst];
    float hd = hdv * a_d;

    float den = 0.f, num = 0.f;
    if (sub == 0) {                           // self-loop
        float v = hdv * a_s + hd;
        v = fmaxf(v, NEG * v);
        float p = __expf(v);
        den = p;
        num = p * hdv;
    }
    for (int i = start + sub; i < end; i += 16) {
        float hs = h2[esrc[i]];
        float v = hs * a_s + hd;
        v = fmaxf(v, NEG * v);
        float p = __expf(v);
        den += p;
        num += p * hs;
    }
    #pragma unroll
    for (int o = 8; o; o >>= 1) {
        den += __shfl_xor(den, o, 16);
        num += __shfl_xor(num, o, 16);
    }
    if (sub == 0) {
        float v = num / (den + 1e-16f) + b2[0];
        out[dst] = 1.f / (1.f + __expf(-v));
    }
}

extern "C" void kernel_launch(void* const* d_in, const int* in_sizes, int n_in,
                              void* d_out, int out_size, void* d_ws, size_t ws_size,
                              hipStream_t stream) {
    const float* x     = (const float*)d_in[0];
    const int*   ei    = (const int*)d_in[1];
    const float* W1    = (const float*)d_in[2];
    const float* atts1 = (const float*)d_in[3];
    const float* attd1 = (const float*)d_in[4];
    const float* b1    = (const float*)d_in[5];
    const float* W2    = (const float*)d_in[6];
    const float* atts2 = (const float*)d_in[7];
    const float* attd2 = (const float*)d_in[8];
    const float* b2    = (const float*)d_in[9];
    float* out = (float*)d_out;

    float* w = (float*)d_ws;
    float* us = w;                       // 32
    float* ud = w + 32;                  // 32
    float* h2 = w + 64;                  // N
    int* ibase  = (int*)(w + 64 + (size_t)NN);
    int* bcnt   = ibase;                           // NBKT (pad 512)
    int* bktoff = ibase + 512;                     // NBKT (pad 512)
    int* row    = ibase + 1024;                    // N+1 (pad N+64)
    int* esrc   = ibase + 1024 + NN + 64;          // NE
    unsigned* bpack = (unsigned*)(ibase + 1024 + NN + 64 + NE);  // NBKT*CAP

    dim3 gW((NN + 3) / 4);            // 25000, wave per dst
    dim3 gF((NN + 15) / 16);          // 6250, 16 dst per block

    hipLaunchKernelGGL(kU_prep, dim3(1), dim3(64), 0, stream, W1, atts1, attd1, us, ud);
    hipMemsetAsync(bcnt, 0, NBKT * sizeof(int), stream);
    hipLaunchKernelGGL(kP1_tile, dim3(NTILE), dim3(1024), 0, stream, ei, bcnt, bpack);
    hipLaunchKernelGGL(kS_scan, dim3(1), dim3(512), 0, stream, bcnt, bktoff, row);
    hipLaunchKernelGGL(kP2_build, dim3(NBKT), dim3(1024), 0, stream, bcnt, bktoff, bpack, row, esrc);
    hipLaunchKernelGGL(kE_l1agg, gW, dim3(256), 0, stream, row, esrc, x, us, ud, W1, b1, W2, h2);
    hipLaunchKernelGGL(kF_l2agg, gF, dim3(256), 0, stream, row, esrc, h2, atts2, attd2, b2, out);
}

// Round 7
// 78.873 us; speedup vs baseline: 8.6955x; 1.4589x over previous
//
#include <hip/hip_runtime.h>

#define NN 100000
#define NE 1600000
#define NBKT 391          // ceil(NN/256) buckets of 256 dst nodes
#define CAP 8192          // bucket capacity (mean 4096, sigma ~64)
#define TILE 16384        // edges per kP1 block
#define NTILE ((NE + TILE - 1) / TILE)   // 98
#define NEG 0.2f

// ---------------- kU: precompute u_s[8][4], u_d[8][4]; zero bcnt ----------------
__global__ __launch_bounds__(512) void kU_prep(
    const float* __restrict__ W1, const float* __restrict__ atts,
    const float* __restrict__ attd, float* __restrict__ us, float* __restrict__ ud,
    int* __restrict__ bcnt)
{
    int t = threadIdx.x;
    if (t < NBKT) bcnt[t] = 0;
    if (t < 64) {
        int half = t >> 5;             // 0: us, 1: ud
        int i = t & 31;
        int h = i >> 2, k = i & 3;
        const float* att = half ? attd : atts;
        float acc = 0.f;
        #pragma unroll
        for (int j = 0; j < 8; j++)
            acc += W1[k * 64 + h * 8 + j] * att[h * 8 + j];
        (half ? ud : us)[h * 4 + k] = acc;
    }
}

// ---------------- kP1: tiled bucket partition (LDS hist + batch reserve + coalesced out) ----------------
__global__ __launch_bounds__(1024) void kP1_tile(
    const int* __restrict__ ei, int* __restrict__ bcnt, unsigned* __restrict__ bpack)
{
    __shared__ unsigned sarr[TILE];          // 64 KB
    __shared__ int lh[512], lsc[512], lgb[512];
    int t = threadIdx.x;
    int e0 = blockIdx.x * TILE;
    int n = NE - e0; if (n > TILE) n = TILE;

    if (t < 512) lh[t] = 0;
    __syncthreads();
    for (int i = t; i < n; i += 1024) {
        int d = ei[NE + e0 + i];
        atomicAdd(&lh[d >> 8], 1);
    }
    __syncthreads();
    if (t < 512) lsc[t] = lh[t];
    __syncthreads();
    #pragma unroll
    for (int o = 1; o < 512; o <<= 1) {
        int u = 0;
        if (t < 512 && t >= o) u = lsc[t - o];
        __syncthreads();
        if (t < 512) lsc[t] += u;
        __syncthreads();
    }
    if (t < NBKT && lh[t] > 0) lgb[t] = atomicAdd(&bcnt[t], lh[t]);
    __syncthreads();
    if (t < 512) lh[t] = lsc[t] - lh[t];
    __syncthreads();
    for (int i = t; i < n; i += 1024) {
        int s = ei[e0 + i], d = ei[NE + e0 + i];
        int b = d >> 8;
        int pos = atomicAdd(&lh[b], 1);
        sarr[pos] = ((unsigned)s << 8) | (unsigned)(d & 255);
    }
    __syncthreads();
    int wave = t >> 6, lane = t & 63;
    for (int b = wave; b < NBKT; b += 16) {
        int start = (b == 0) ? 0 : lsc[b - 1];
        int cntb = lsc[b] - start;
        if (cntb == 0) continue;
        int gb = lgb[b];
        unsigned* dstp = &bpack[(size_t)b * CAP];
        for (int j = lane; j < cntb; j += 64) {
            int gpos = gb + j;
            if (gpos < CAP) dstp[gpos] = sarr[start + j];
        }
    }
}

// ---------------- kS: exclusive scan of bucket counts (single block) ----------------
__global__ __launch_bounds__(512) void kS_scan(
    const int* __restrict__ bcnt, int* __restrict__ bktoff, int* __restrict__ row)
{
    __shared__ int s[512];
    int t = threadIdx.x;
    int v = (t < NBKT) ? bcnt[t] : 0;
    s[t] = v;
    __syncthreads();
    #pragma unroll
    for (int o = 1; o < 512; o <<= 1) {
        int u = (t >= o) ? s[t - o] : 0;
        __syncthreads();
        s[t] += u;
        __syncthreads();
    }
    if (t < NBKT) bktoff[t] = s[t] - v;
    if (t == 0) row[NN] = NE;
}

// ---------------- kP2: per-bucket LDS counting sort -> row + esrc ----------------
__global__ __launch_bounds__(1024) void kP2_build(
    const int* __restrict__ bcnt, const int* __restrict__ bktoff,
    const unsigned* __restrict__ bpack, int* __restrict__ row, int* __restrict__ esrc)
{
    __shared__ int lh[256], lsc[256], lcur[256];
    __shared__ int sarr[CAP];
    int b = blockIdx.x;
    int t = threadIdx.x;
    int cnt = bcnt[b];
    if (cnt > CAP) cnt = CAP;
    const unsigned* bp = &bpack[(size_t)b * CAP];
    if (t < 256) lh[t] = 0;
    __syncthreads();
    for (int i = t; i < cnt; i += 1024)
        atomicAdd(&lh[bp[i] & 255u], 1);
    __syncthreads();
    if (t < 256) lsc[t] = lh[t];
    __syncthreads();
    #pragma unroll
    for (int o = 1; o < 256; o <<= 1) {
        int u = 0;
        if (t < 256 && t >= o) u = lsc[t - o];
        __syncthreads();
        if (t < 256) lsc[t] += u;
        __syncthreads();
    }
    int base = bktoff[b];
    if (t < 256) {
        int ex = lsc[t] - lh[t];
        lcur[t] = ex;
        int node = b * 256 + t;
        if (node < NN) row[node] = base + ex;
    }
    __syncthreads();
    for (int i = t; i < cnt; i += 1024) {
        unsigned u = bp[i];
        int pos = atomicAdd(&lcur[u & 255u], 1);
        sarr[pos] = (int)(u >> 8);
    }
    __syncthreads();
    for (int i = t; i < cnt; i += 1024)
        esrc[base + i] = sarr[i];
}

// ---------------- kE: layer-1: 16 lanes/dst (2 slots x 8 heads), 4 dst/wave ----------------
__global__ __launch_bounds__(256) void kE_l1agg(
    const int* __restrict__ row, const int* __restrict__ esrc,
    const float* __restrict__ x, const float* __restrict__ us,
    const float* __restrict__ ud, const float* __restrict__ W1,
    const float* __restrict__ b1, const float* __restrict__ W2,
    float* __restrict__ h2)
{
    int t = threadIdx.x;
    int grp = t >> 4;               // 16 dst-groups per block
    int sub = t & 15;
    int dst = blockIdx.x * 16 + grp;
    if (dst >= NN) return;
    int slot = sub >> 3;            // 0..1
    int h    = sub & 7;             // head

    int start = row[dst], end = row[dst + 1];
    int m = end - start;            // real in-edges; slot j==m is the self-loop

    float4 u  = *reinterpret_cast<const float4*>(&us[h * 4]);
    float4 vd = *reinterpret_cast<const float4*>(&ud[h * 4]);
    float4 xd = *reinterpret_cast<const float4*>(&x[(size_t)dst * 4]);
    float adj = xd.x * vd.x + xd.y * vd.y + xd.z * vd.z + xd.w * vd.w;

    // per-edge: p = exp(leaky(x[s].u_h + adj)); xagg += p*x[s]; den += p
    float xa0 = 0.f, xa1 = 0.f, xa2 = 0.f, xa3 = 0.f, den = 0.f;
    for (int j = slot; j <= m; j += 2) {
        int s = (j < m) ? esrc[start + j] : dst;
        float4 xs = *reinterpret_cast<const float4*>(&x[(size_t)s * 4]);
        float a = fmaf(xs.x, u.x, fmaf(xs.y, u.y, fmaf(xs.z, u.z, fmaf(xs.w, u.w, adj))));
        a = fmaxf(a, NEG * a);                // leaky_relu
        float p = __expf(a);                  // softmax shift-invariant; logits bounded
        den += p;
        xa0 = fmaf(p, xs.x, xa0);
        xa1 = fmaf(p, xs.y, xa1);
        xa2 = fmaf(p, xs.z, xa2);
        xa3 = fmaf(p, xs.w, xa3);
    }
    // combine the two slots (xor 8 within the 16-lane group)
    xa0 += __shfl_xor(xa0, 8, 16);
    xa1 += __shfl_xor(xa1, 8, 16);
    xa2 += __shfl_xor(xa2, 8, 16);
    xa3 += __shfl_xor(xa3, 8, 16);
    den += __shfl_xor(den, 8, 16);

    // each lane projects 4 contiguous channels: c0 = h*8 + slot*4
    int c0 = h * 8 + slot * 4;
    float4 w0 = *reinterpret_cast<const float4*>(&W1[c0]);
    float4 w1 = *reinterpret_cast<const float4*>(&W1[64 + c0]);
    float4 w2 = *reinterpret_cast<const float4*>(&W1[128 + c0]);
    float4 w3 = *reinterpret_cast<const float4*>(&W1[192 + c0]);
    float4 bb = *reinterpret_cast<const float4*>(&b1[c0]);
    float4 ww = *reinterpret_cast<const float4*>(&W2[c0]);
    float inv = 1.f / (den + 1e-16f);

    float acc;
    {
        float v = (xa0 * w0.x + xa1 * w1.x + xa2 * w2.x + xa3 * w3.x) * inv + bb.x;
        v = v > 0.f ? v : (__expf(v) - 1.f);
        acc = v * ww.x;
    }
    {
        float v = (xa0 * w0.y + xa1 * w1.y + xa2 * w2.y + xa3 * w3.y) * inv + bb.y;
        v = v > 0.f ? v : (__expf(v) - 1.f);
        acc += v * ww.y;
    }
    {
        float v = (xa0 * w0.z + xa1 * w1.z + xa2 * w2.z + xa3 * w3.z) * inv + bb.z;
        v = v > 0.f ? v : (__expf(v) - 1.f);
        acc += v * ww.z;
    }
    {
        float v = (xa0 * w0.w + xa1 * w1.w + xa2 * w2.w + xa3 * w3.w) * inv + bb.w;
        v = v > 0.f ? v : (__expf(v) - 1.f);
        acc += v * ww.w;
    }
    // reduce the 16 lanes' 4-channel partials -> full 64-channel dot
    #pragma unroll
    for (int o = 1; o < 16; o <<= 1) acc += __shfl_xor(acc, o, 16);
    if (sub == 0) h2[dst] = acc;
}

// ---------------- kF: layer-2 aggregate + sigmoid (16 lanes per dst) ----------------
__global__ __launch_bounds__(256) void kF_l2agg(
    const int* __restrict__ row, const int* __restrict__ esrc,
    const float* __restrict__ h2, const float* __restrict__ as2,
    const float* __restrict__ ad2, const float* __restrict__ b2,
    float* __restrict__ out)
{
    int grp = threadIdx.x >> 4;
    int sub = threadIdx.x & 15;
    int dst = blockIdx.x * 16 + grp;
    if (dst >= NN) return;
    int start = row[dst], end = row[dst + 1];
    float a_s = as2[0], a_d = ad2[0];
    float hdv = h2[dst];
    float hd = hdv * a_d;

    float den = 0.f, num = 0.f;
    if (sub == 0) {                           // self-loop
        float v = hdv * a_s + hd;
        v = fmaxf(v, NEG * v);
        float p = __expf(v);
        den = p;
        num = p * hdv;
    }
    for (int i = start + sub; i < end; i += 16) {
        float hs = h2[esrc[i]];
        float v = hs * a_s + hd;
        v = fmaxf(v, NEG * v);
        float p = __expf(v);
        den += p;
        num += p * hs;
    }
    #pragma unroll
    for (int o = 8; o; o >>= 1) {
        den += __shfl_xor(den, o, 16);
        num += __shfl_xor(num, o, 16);
    }
    if (sub == 0) {
        float v = num / (den + 1e-16f) + b2[0];
        out[dst] = 1.f / (1.f + __expf(-v));
    }
}

extern "C" void kernel_launch(void* const* d_in, const int* in_sizes, int n_in,
                              void* d_out, int out_size, void* d_ws, size_t ws_size,
                              hipStream_t stream) {
    const float* x     = (const float*)d_in[0];
    const int*   ei    = (const int*)d_in[1];
    const float* W1    = (const float*)d_in[2];
    const float* atts1 = (const float*)d_in[3];
    const float* attd1 = (const float*)d_in[4];
    const float* b1    = (const float*)d_in[5];
    const float* W2    = (const float*)d_in[6];
    const float* atts2 = (const float*)d_in[7];
    const float* attd2 = (const float*)d_in[8];
    const float* b2    = (const float*)d_in[9];
    float* out = (float*)d_out;

    float* w = (float*)d_ws;
    float* us = w;                       // 32
    float* ud = w + 32;                  // 32
    float* h2 = w + 64;                  // N
    int* ibase  = (int*)(w + 64 + (size_t)NN);
    int* bcnt   = ibase;                           // NBKT (pad 512)
    int* bktoff = ibase + 512;                     // NBKT (pad 512)
    int* row    = ibase + 1024;                    // N+1 (pad N+64)
    int* esrc   = ibase + 1024 + NN + 64;          // NE
    unsigned* bpack = (unsigned*)(ibase + 1024 + NN + 64 + NE);  // NBKT*CAP

    dim3 gG((NN + 15) / 16);          // 6250, 16 dst per block

    hipLaunchKernelGGL(kU_prep, dim3(1), dim3(512), 0, stream, W1, atts1, attd1, us, ud, bcnt);
    hipLaunchKernelGGL(kP1_tile, dim3(NTILE), dim3(1024), 0, stream, ei, bcnt, bpack);
    hipLaunchKernelGGL(kS_scan, dim3(1), dim3(512), 0, stream, bcnt, bktoff, row);
    hipLaunchKernelGGL(kP2_build, dim3(NBKT), dim3(1024), 0, stream, bcnt, bktoff, bpack, row, esrc);
    hipLaunchKernelGGL(kE_l1agg, gG, dim3(256), 0, stream, row, esrc, x, us, ud, W1, b1, W2, h2);
    hipLaunchKernelGGL(kF_l2agg, gG, dim3(256), 0, stream, row, esrc, h2, atts2, attd2, b2, out);
}

// Round 8
// 75.575 us; speedup vs baseline: 9.0749x; 1.0436x over previous
//
#include <hip/hip_runtime.h>

#define NN 100000
#define NE 1600000
#define NBKT 391          // ceil(NN/256) buckets of 256 dst nodes
#define CAP 8192          // bucket capacity (mean 4096, sigma ~64)
#define TILE 4096         // edges per kP1 block
#define NTILE ((NE + TILE - 1) / TILE)   // 391
#define NEG 0.2f

// ---------------- kU: precompute u_s[8][4], u_d[8][4]; zero bcnt ----------------
__global__ __launch_bounds__(512) void kU_prep(
    const float* __restrict__ W1, const float* __restrict__ atts,
    const float* __restrict__ attd, float* __restrict__ us, float* __restrict__ ud,
    int* __restrict__ bcnt)
{
    int t = threadIdx.x;
    if (t < NBKT) bcnt[t] = 0;
    if (t < 64) {
        int half = t >> 5;             // 0: us, 1: ud
        int i = t & 31;
        int h = i >> 2, k = i & 3;
        const float* att = half ? attd : atts;
        float acc = 0.f;
        #pragma unroll
        for (int j = 0; j < 8; j++)
            acc += W1[k * 64 + h * 8 + j] * att[h * 8 + j];
        (half ? ud : us)[h * 4 + k] = acc;
    }
}

// ---------------- kP1: tiled bucket partition (LDS hist + batch reserve + coalesced out) ----------------
__global__ __launch_bounds__(1024) void kP1_tile(
    const int* __restrict__ ei, int* __restrict__ bcnt, unsigned* __restrict__ bpack)
{
    __shared__ unsigned sarr[TILE];          // 16 KB
    __shared__ int lh[512], lsc[512], lgb[512];
    int t = threadIdx.x;
    int e0 = blockIdx.x * TILE;
    int n = NE - e0; if (n > TILE) n = TILE;

    if (t < 512) lh[t] = 0;
    __syncthreads();
    for (int i = t; i < n; i += 1024) {
        int d = ei[NE + e0 + i];
        atomicAdd(&lh[d >> 8], 1);
    }
    __syncthreads();
    if (t < 512) lsc[t] = lh[t];
    __syncthreads();
    #pragma unroll
    for (int o = 1; o < 512; o <<= 1) {
        int u = 0;
        if (t < 512 && t >= o) u = lsc[t - o];
        __syncthreads();
        if (t < 512) lsc[t] += u;
        __syncthreads();
    }
    if (t < NBKT && lh[t] > 0) lgb[t] = atomicAdd(&bcnt[t], lh[t]);
    __syncthreads();
    if (t < 512) lh[t] = lsc[t] - lh[t];
    __syncthreads();
    for (int i = t; i < n; i += 1024) {
        int s = ei[e0 + i], d = ei[NE + e0 + i];
        int b = d >> 8;
        int pos = atomicAdd(&lh[b], 1);
        sarr[pos] = ((unsigned)s << 8) | (unsigned)(d & 255);
    }
    __syncthreads();
    int wave = t >> 6, lane = t & 63;
    for (int b = wave; b < NBKT; b += 16) {
        int start = (b == 0) ? 0 : lsc[b - 1];
        int cntb = lsc[b] - start;
        if (cntb == 0) continue;
        int gb = lgb[b];
        unsigned* dstp = &bpack[(size_t)b * CAP];
        for (int j = lane; j < cntb; j += 64) {
            int gpos = gb + j;
            if (gpos < CAP) dstp[gpos] = sarr[start + j];
        }
    }
}

// ---------------- kS: exclusive scan of bucket counts (single block) ----------------
__global__ __launch_bounds__(512) void kS_scan(
    const int* __restrict__ bcnt, int* __restrict__ bktoff, int* __restrict__ row)
{
    __shared__ int s[512];
    int t = threadIdx.x;
    int v = (t < NBKT) ? bcnt[t] : 0;
    s[t] = v;
    __syncthreads();
    #pragma unroll
    for (int o = 1; o < 512; o <<= 1) {
        int u = (t >= o) ? s[t - o] : 0;
        __syncthreads();
        s[t] += u;
        __syncthreads();
    }
    if (t < NBKT) bktoff[t] = s[t] - v;
    if (t == 0) row[NN] = NE;
}

// ---------------- kP2: per-bucket LDS counting sort -> row + esrc ----------------
__global__ __launch_bounds__(1024) void kP2_build(
    const int* __restrict__ bcnt, const int* __restrict__ bktoff,
    const unsigned* __restrict__ bpack, int* __restrict__ row, int* __restrict__ esrc)
{
    __shared__ int lh[256], lsc[256], lcur[256];
    __shared__ int sarr[CAP];
    int b = blockIdx.x;
    int t = threadIdx.x;
    int cnt = bcnt[b];
    if (cnt > CAP) cnt = CAP;
    const unsigned* bp = &bpack[(size_t)b * CAP];
    if (t < 256) lh[t] = 0;
    __syncthreads();
    for (int i = t; i < cnt; i += 1024)
        atomicAdd(&lh[bp[i] & 255u], 1);
    __syncthreads();
    if (t < 256) lsc[t] = lh[t];
    __syncthreads();
    #pragma unroll
    for (int o = 1; o < 256; o <<= 1) {
        int u = 0;
        if (t < 256 && t >= o) u = lsc[t - o];
        __syncthreads();
        if (t < 256) lsc[t] += u;
        __syncthreads();
    }
    int base = bktoff[b];
    if (t < 256) {
        int ex = lsc[t] - lh[t];
        lcur[t] = ex;
        int node = b * 256 + t;
        if (node < NN) row[node] = base + ex;
    }
    __syncthreads();
    for (int i = t; i < cnt; i += 1024) {
        unsigned u = bp[i];
        int pos = atomicAdd(&lcur[u & 255u], 1);
        sarr[pos] = (int)(u >> 8);
    }
    __syncthreads();
    for (int i = t; i < cnt; i += 1024)
        esrc[base + i] = sarr[i];
}

// ---------------- kE: layer-1: 8 lanes/dst (8 heads), 8 dst/wave, unroll 2 ----------------
__global__ __launch_bounds__(256) void kE_l1agg(
    const int* __restrict__ row, const int* __restrict__ esrc,
    const float* __restrict__ x, const float* __restrict__ us,
    const float* __restrict__ ud, const float* __restrict__ W1,
    const float* __restrict__ b1, const float* __restrict__ W2,
    float* __restrict__ h2)
{
    int t = threadIdx.x;
    int grp = t >> 3;               // 32 dst-groups per block
    int h   = t & 7;                // head
    int dst = blockIdx.x * 32 + grp;
    if (dst >= NN) return;

    int start = row[dst], end = row[dst + 1];
    int m = end - start;            // real in-edges

    float4 u  = *reinterpret_cast<const float4*>(&us[h * 4]);
    float4 vd = *reinterpret_cast<const float4*>(&ud[h * 4]);
    float4 xd = *reinterpret_cast<const float4*>(&x[(size_t)dst * 4]);
    float adj = xd.x * vd.x + xd.y * vd.y + xd.z * vd.z + xd.w * vd.w;

    // self-loop (peeled)
    float a0 = fmaf(xd.x, u.x, fmaf(xd.y, u.y, fmaf(xd.z, u.z, fmaf(xd.w, u.w, adj))));
    a0 = fmaxf(a0, NEG * a0);
    float p0 = __expf(a0);
    float den = p0;
    float xa0 = p0 * xd.x, xa1 = p0 * xd.y, xa2 = p0 * xd.z, xa3 = p0 * xd.w;

    int j = 0;
    for (; j + 2 <= m; j += 2) {
        int s0 = esrc[start + j];
        int s1 = esrc[start + j + 1];
        float4 q0 = *reinterpret_cast<const float4*>(&x[(size_t)s0 * 4]);
        float4 q1 = *reinterpret_cast<const float4*>(&x[(size_t)s1 * 4]);
        float b0 = fmaf(q0.x, u.x, fmaf(q0.y, u.y, fmaf(q0.z, u.z, fmaf(q0.w, u.w, adj))));
        float c1 = fmaf(q1.x, u.x, fmaf(q1.y, u.y, fmaf(q1.z, u.z, fmaf(q1.w, u.w, adj))));
        b0 = fmaxf(b0, NEG * b0);
        c1 = fmaxf(c1, NEG * c1);
        float pb = __expf(b0);
        float pc = __expf(c1);
        den += pb + pc;
        xa0 = fmaf(pb, q0.x, fmaf(pc, q1.x, xa0));
        xa1 = fmaf(pb, q0.y, fmaf(pc, q1.y, xa1));
        xa2 = fmaf(pb, q0.z, fmaf(pc, q1.z, xa2));
        xa3 = fmaf(pb, q0.w, fmaf(pc, q1.w, xa3));
    }
    if (j < m) {
        int s0 = esrc[start + j];
        float4 q0 = *reinterpret_cast<const float4*>(&x[(size_t)s0 * 4]);
        float b0 = fmaf(q0.x, u.x, fmaf(q0.y, u.y, fmaf(q0.z, u.z, fmaf(q0.w, u.w, adj))));
        b0 = fmaxf(b0, NEG * b0);
        float pb = __expf(b0);
        den += pb;
        xa0 = fmaf(pb, q0.x, xa0);
        xa1 = fmaf(pb, q0.y, xa1);
        xa2 = fmaf(pb, q0.z, xa2);
        xa3 = fmaf(pb, q0.w, xa3);
    }

    // projection: lane handles its head's 8 channels c = h*8..h*8+7
    int c0 = h * 8;
    float4 w0l = *reinterpret_cast<const float4*>(&W1[c0]);
    float4 w0h = *reinterpret_cast<const float4*>(&W1[c0 + 4]);
    float4 w1l = *reinterpret_cast<const float4*>(&W1[64 + c0]);
    float4 w1h = *reinterpret_cast<const float4*>(&W1[64 + c0 + 4]);
    float4 w2l = *reinterpret_cast<const float4*>(&W1[128 + c0]);
    float4 w2h = *reinterpret_cast<const float4*>(&W1[128 + c0 + 4]);
    float4 w3l = *reinterpret_cast<const float4*>(&W1[192 + c0]);
    float4 w3h = *reinterpret_cast<const float4*>(&W1[192 + c0 + 4]);
    float4 bbl = *reinterpret_cast<const float4*>(&b1[c0]);
    float4 bbh = *reinterpret_cast<const float4*>(&b1[c0 + 4]);
    float4 wwl = *reinterpret_cast<const float4*>(&W2[c0]);
    float4 wwh = *reinterpret_cast<const float4*>(&W2[c0 + 4]);
    float inv = 1.f / (den + 1e-16f);

    float acc = 0.f;
    {
        float v;
        v = (xa0*w0l.x + xa1*w1l.x + xa2*w2l.x + xa3*w3l.x)*inv + bbl.x;
        v = v > 0.f ? v : (__expf(v) - 1.f);  acc += v * wwl.x;
        v = (xa0*w0l.y + xa1*w1l.y + xa2*w2l.y + xa3*w3l.y)*inv + bbl.y;
        v = v > 0.f ? v : (__expf(v) - 1.f);  acc += v * wwl.y;
        v = (xa0*w0l.z + xa1*w1l.z + xa2*w2l.z + xa3*w3l.z)*inv + bbl.z;
        v = v > 0.f ? v : (__expf(v) - 1.f);  acc += v * wwl.z;
        v = (xa0*w0l.w + xa1*w1l.w + xa2*w2l.w + xa3*w3l.w)*inv + bbl.w;
        v = v > 0.f ? v : (__expf(v) - 1.f);  acc += v * wwl.w;
        v = (xa0*w0h.x + xa1*w1h.x + xa2*w2h.x + xa3*w3h.x)*inv + bbh.x;
        v = v > 0.f ? v : (__expf(v) - 1.f);  acc += v * wwh.x;
        v = (xa0*w0h.y + xa1*w1h.y + xa2*w2h.y + xa3*w3h.y)*inv + bbh.y;
        v = v > 0.f ? v : (__expf(v) - 1.f);  acc += v * wwh.y;
        v = (xa0*w0h.z + xa1*w1h.z + xa2*w2h.z + xa3*w3h.z)*inv + bbh.z;
        v = v > 0.f ? v : (__expf(v) - 1.f);  acc += v * wwh.z;
        v = (xa0*w0h.w + xa1*w1h.w + xa2*w2h.w + xa3*w3h.w)*inv + bbh.w;
        v = v > 0.f ? v : (__expf(v) - 1.f);  acc += v * wwh.w;
    }
    // reduce 8 heads (width 8)
    acc += __shfl_xor(acc, 1, 8);
    acc += __shfl_xor(acc, 2, 8);
    acc += __shfl_xor(acc, 4, 8);
    if (h == 0) h2[dst] = acc;
}

// ---------------- kF: layer-2 aggregate + sigmoid (8 lanes per dst, unroll 2) ----------------
__global__ __launch_bounds__(256) void kF_l2agg(
    const int* __restrict__ row, const int* __restrict__ esrc,
    const float* __restrict__ h2, const float* __restrict__ as2,
    const float* __restrict__ ad2, const float* __restrict__ b2,
    float* __restrict__ out)
{
    int t = threadIdx.x;
    int grp = t >> 3;
    int sub = t & 7;
    int dst = blockIdx.x * 32 + grp;
    if (dst >= NN) return;
    int start = row[dst], end = row[dst + 1];
    float a_s = as2[0], a_d = ad2[0];
    float hdv = h2[dst];
    float hd = hdv * a_d;

    float den = 0.f, num = 0.f;
    if (sub == 0) {                           // self-loop
        float v = hdv * a_s + hd;
        v = fmaxf(v, NEG * v);
        float p = __expf(v);
        den = p;
        num = p * hdv;
    }
    int i = start + sub;
    for (; i + 8 < end; i += 16) {
        float hs0 = h2[esrc[i]];
        float hs1 = h2[esrc[i + 8]];
        float v0 = hs0 * a_s + hd;
        float v1 = hs1 * a_s + hd;
        v0 = fmaxf(v0, NEG * v0);
        v1 = fmaxf(v1, NEG * v1);
        float p0 = __expf(v0);
        float p1 = __expf(v1);
        den += p0 + p1;
        num = fmaf(p0, hs0, fmaf(p1, hs1, num));
    }
    if (i < end) {
        float hs = h2[esrc[i]];
        float v = hs * a_s + hd;
        v = fmaxf(v, NEG * v);
        float p = __expf(v);
        den += p;
        num = fmaf(p, hs, num);
    }
    den += __shfl_xor(den, 1, 8);
    num += __shfl_xor(num, 1, 8);
    den += __shfl_xor(den, 2, 8);
    num += __shfl_xor(num, 2, 8);
    den += __shfl_xor(den, 4, 8);
    num += __shfl_xor(num, 4, 8);
    if (sub == 0) {
        float v = num / (den + 1e-16f) + b2[0];
        out[dst] = 1.f / (1.f + __expf(-v));
    }
}

extern "C" void kernel_launch(void* const* d_in, const int* in_sizes, int n_in,
                              void* d_out, int out_size, void* d_ws, size_t ws_size,
                              hipStream_t stream) {
    const float* x     = (const float*)d_in[0];
    const int*   ei    = (const int*)d_in[1];
    const float* W1    = (const float*)d_in[2];
    const float* atts1 = (const float*)d_in[3];
    const float* attd1 = (const float*)d_in[4];
    const float* b1    = (const float*)d_in[5];
    const float* W2    = (const float*)d_in[6];
    const float* atts2 = (const float*)d_in[7];
    const float* attd2 = (const float*)d_in[8];
    const float* b2    = (const float*)d_in[9];
    float* out = (float*)d_out;

    float* w = (float*)d_ws;
    float* us = w;                       // 32
    float* ud = w + 32;                  // 32
    float* h2 = w + 64;                  // N
    int* ibase  = (int*)(w + 64 + (size_t)NN);
    int* bcnt   = ibase;                           // NBKT (pad 512)
    int* bktoff = ibase + 512;                     // NBKT (pad 512)
    int* row    = ibase + 1024;                    // N+1 (pad N+64)
    int* esrc   = ibase + 1024 + NN + 64;          // NE
    unsigned* bpack = (unsigned*)(ibase + 1024 + NN + 64 + NE);  // NBKT*CAP

    dim3 gG((NN + 31) / 32);          // 3125, 32 dst per block

    hipLaunchKernelGGL(kU_prep, dim3(1), dim3(512), 0, stream, W1, atts1, attd1, us, ud, bcnt);
    hipLaunchKernelGGL(kP1_tile, dim3(NTILE), dim3(1024), 0, stream, ei, bcnt, bpack);
    hipLaunchKernelGGL(kS_scan, dim3(1), dim3(512), 0, stream, bcnt, bktoff, row);
    hipLaunchKernelGGL(kP2_build, dim3(NBKT), dim3(1024), 0, stream, bcnt, bktoff, bpack, row, esrc);
    hipLaunchKernelGGL(kE_l1agg, gG, dim3(256), 0, stream, row, esrc, x, us, ud, W1, b1, W2, h2);
    hipLaunchKernelGGL(kF_l2agg, gG, dim3(256), 0, stream, row, esrc, h2, atts2, attd2, b2, out);
}